// Round 23
// baseline (815.088 us; speedup 1.0000x reference)
//
#include <hip/hip_runtime.h>
#include <math.h>

#define NB 2
#define NT 2048
#define NH 16
#define DH 64
#define DM 1024

using bf8   = __attribute__((ext_vector_type(8))) short;
using f32x4 = __attribute__((ext_vector_type(4))) float;

static __device__ __forceinline__ ushort f2bf(float f) {
    union { float f; unsigned u; } c; c.f = f;
    unsigned u = c.u + 0x7FFFu + ((c.u >> 16) & 1u);
    return (ushort)(u >> 16);
}
static __device__ __forceinline__ float bf2f(ushort u) {
    union { unsigned u; float f; } c; c.u = ((unsigned)u) << 16;
    return c.f;
}

// Alpert basis W_b (CHUNK=16, K=2): col0 = 1/4, col1 = t/||t||, t=linspace(-1,1,16)
static __device__ __forceinline__ float wbf(int l, int k) {
    if (k == 0) return 0.25f;
    const float invn = 1.0f / sqrtf(1360.0f / 225.0f);
    return (-1.0f + (2.0f / 15.0f) * (float)l) * invn;
}

// ---------- cast x, Wv, Wo to bf16 ----------
__global__ __launch_bounds__(256) void cast3_kernel(
    const float* __restrict__ x, const float* __restrict__ wv,
    const float* __restrict__ wo, ushort* __restrict__ xb, ushort* __restrict__ wb)
{
    const int id = blockIdx.x * 256 + threadIdx.x;
    const int XQ = (NB * NT * DM) / 4;
    const int WQ = (DM * DM) / 4;
    const float4* src;
    ushort* dst;
    if (id < XQ) {
        src = (const float4*)x + id;
        dst = xb + (size_t)id * 4;
    } else {
        const int r = id - XQ;
        const int wi = r / WQ, off = r % WQ;
        const float* w = (wi == 0) ? wv : wo;
        src = (const float4*)w + off;
        dst = wb + (size_t)wi * DM * DM + (size_t)off * 4;
    }
    const float4 v = *src;
    ushort4 o;
    o.x = f2bf(v.x); o.y = f2bf(v.y); o.z = f2bf(v.z); o.w = f2bf(v.w);
    *(ushort4*)dst = o;
}

// ---------- q/k/gate projections via bf16x3 MFMA emulation (6 products, fp32-level accuracy) ----------
__global__ __launch_bounds__(256) void gemm3m_kernel(
    const float* __restrict__ x, const float* __restrict__ Wq,
    const float* __restrict__ Wk, const float* __restrict__ gw,
    const float* __restrict__ gbias,
    float* __restrict__ oq, float* __restrict__ ok, float* __restrict__ og)
{
    __shared__ ushort Ah[128][40], Am[128][40], Al[128][40];
    __shared__ ushort Bh[64][40],  Bm[64][40],  Bl[64][40];
    const int z = blockIdx.z;
    const float* Bw = (z == 0) ? Wq : (z == 1) ? Wk : gw;
    float* C = (z == 0) ? oq : (z == 1) ? ok : og;
    const int tid = threadIdx.x;
    const int l = tid & 63, w = tid >> 6;
    const int wr = w >> 1, wc = w & 1;
    const int lr = l & 15, g = l >> 4;
    const int row0 = blockIdx.y * 128, col0 = blockIdx.x * 64;
    f32x4 acc[4][2];
    #pragma unroll
    for (int mi = 0; mi < 4; ++mi)
        #pragma unroll
        for (int ni = 0; ni < 2; ++ni) acc[mi][ni] = (f32x4){0.f, 0.f, 0.f, 0.f};
    const int sa_row = tid >> 1, sa_col = (tid & 1) * 16;
    const int sb_row = tid >> 2, sb_col = (tid & 3) * 8;
    const float* Ap = x  + (size_t)(row0 + sa_row) * DM + sa_col;
    const float* Bp = Bw + (size_t)(col0 + sb_row) * DM + sb_col;
    for (int k0 = 0; k0 < DM; k0 += 32) {
        float av[16], bv[8];
        *(float4*)&av[0]  = *(const float4*)(Ap + k0);
        *(float4*)&av[4]  = *(const float4*)(Ap + k0 + 4);
        *(float4*)&av[8]  = *(const float4*)(Ap + k0 + 8);
        *(float4*)&av[12] = *(const float4*)(Ap + k0 + 12);
        *(float4*)&bv[0]  = *(const float4*)(Bp + k0);
        *(float4*)&bv[4]  = *(const float4*)(Bp + k0 + 4);
        __syncthreads();
        #pragma unroll
        for (int c = 0; c < 16; c += 4) {
            ushort4 hh, mm, ll;
            ushort* hp = (ushort*)&hh;
            ushort* mp = (ushort*)&mm;
            ushort* lp = (ushort*)&ll;
            #pragma unroll
            for (int u = 0; u < 4; ++u) {
                const float v = av[c + u];
                const ushort hu = f2bf(v);
                const float r1 = v - bf2f(hu);
                const ushort mu = f2bf(r1);
                const ushort lu = f2bf(r1 - bf2f(mu));
                hp[u] = hu; mp[u] = mu; lp[u] = lu;
            }
            *(ushort4*)&Ah[sa_row][sa_col + c] = hh;
            *(ushort4*)&Am[sa_row][sa_col + c] = mm;
            *(ushort4*)&Al[sa_row][sa_col + c] = ll;
        }
        #pragma unroll
        for (int c = 0; c < 8; c += 4) {
            ushort4 hh, mm, ll;
            ushort* hp = (ushort*)&hh;
            ushort* mp = (ushort*)&mm;
            ushort* lp = (ushort*)&ll;
            #pragma unroll
            for (int u = 0; u < 4; ++u) {
                const float v = bv[c + u];
                const ushort hu = f2bf(v);
                const float r1 = v - bf2f(hu);
                const ushort mu = f2bf(r1);
                const ushort lu = f2bf(r1 - bf2f(mu));
                hp[u] = hu; mp[u] = mu; lp[u] = lu;
            }
            *(ushort4*)&Bh[sb_row][sb_col + c] = hh;
            *(ushort4*)&Bm[sb_row][sb_col + c] = mm;
            *(ushort4*)&Bl[sb_row][sb_col + c] = ll;
        }
        __syncthreads();
        bf8 ah[4], am[4], al[4], bh[2], bm[2], bl[2];
        #pragma unroll
        for (int mi = 0; mi < 4; ++mi) {
            ah[mi] = *(const bf8*)&Ah[wr * 64 + mi * 16 + lr][g * 8];
            am[mi] = *(const bf8*)&Am[wr * 64 + mi * 16 + lr][g * 8];
            al[mi] = *(const bf8*)&Al[wr * 64 + mi * 16 + lr][g * 8];
        }
        #pragma unroll
        for (int ni = 0; ni < 2; ++ni) {
            bh[ni] = *(const bf8*)&Bh[wc * 32 + ni * 16 + lr][g * 8];
            bm[ni] = *(const bf8*)&Bm[wc * 32 + ni * 16 + lr][g * 8];
            bl[ni] = *(const bf8*)&Bl[wc * 32 + ni * 16 + lr][g * 8];
        }
        #pragma unroll
        for (int mi = 0; mi < 4; ++mi)
            #pragma unroll
            for (int ni = 0; ni < 2; ++ni) {
                acc[mi][ni] = __builtin_amdgcn_mfma_f32_16x16x32_bf16(ah[mi], bh[ni], acc[mi][ni], 0, 0, 0);
                acc[mi][ni] = __builtin_amdgcn_mfma_f32_16x16x32_bf16(ah[mi], bm[ni], acc[mi][ni], 0, 0, 0);
                acc[mi][ni] = __builtin_amdgcn_mfma_f32_16x16x32_bf16(am[mi], bh[ni], acc[mi][ni], 0, 0, 0);
                acc[mi][ni] = __builtin_amdgcn_mfma_f32_16x16x32_bf16(am[mi], bm[ni], acc[mi][ni], 0, 0, 0);
                acc[mi][ni] = __builtin_amdgcn_mfma_f32_16x16x32_bf16(ah[mi], bl[ni], acc[mi][ni], 0, 0, 0);
                acc[mi][ni] = __builtin_amdgcn_mfma_f32_16x16x32_bf16(al[mi], bh[ni], acc[mi][ni], 0, 0, 0);
            }
    }
    #pragma unroll
    for (int mi = 0; mi < 4; ++mi) {
        const int m0 = row0 + wr * 64 + mi * 16 + g * 4;
        const int bb = m0 >> 11, t0 = m0 & 2047;
        #pragma unroll
        for (int ni = 0; ni < 2; ++ni) {
            const int n = col0 + wc * 32 + ni * 16 + lr;
            const int h = n >> 6, dh = n & 63;
            #pragma unroll
            for (int r = 0; r < 4; ++r) {
                float v = acc[mi][ni][r];
                if (z == 2) v = 1.0f / (1.0f + __expf(-(v + gbias[n])));
                C[(((size_t)(bb * NH + h)) * NT + (t0 + r)) * DH + dh] = v;
            }
        }
    }
}

// ---------- bf16 MFMA GEMM (Wo path, fp32 row-major out) ----------
__global__ __launch_bounds__(256) void gemm_bf16_kernel(
    const ushort* __restrict__ Ab, const ushort* __restrict__ Bb,
    float* __restrict__ Cp)
{
    __shared__ ushort Al[128][40];
    __shared__ ushort Bl[64][40];
    const int tid = threadIdx.x;
    const int l = tid & 63, w = tid >> 6;
    const int wr = w >> 1, wc = w & 1;
    const int lr = l & 15, g = l >> 4;
    const int row0 = blockIdx.y * 128, col0 = blockIdx.x * 64;
    f32x4 acc[4][2];
    #pragma unroll
    for (int mi = 0; mi < 4; ++mi)
        #pragma unroll
        for (int ni = 0; ni < 2; ++ni) acc[mi][ni] = (f32x4){0.f, 0.f, 0.f, 0.f};
    const int sa_row = tid >> 1, sa_half = (tid & 1) * 16;
    const int sb_row = tid >> 2, sb_q = (tid & 3) * 8;
    const ushort* Ap = Ab + (size_t)(row0 + sa_row) * DM + sa_half;
    const ushort* Bp = Bb + (size_t)(col0 + sb_row) * DM + sb_q;
    for (int k0 = 0; k0 < DM; k0 += 32) {
        const uint4 a0 = *(const uint4*)(Ap + k0);
        const uint4 a1 = *(const uint4*)(Ap + k0 + 8);
        const uint4 b0 = *(const uint4*)(Bp + k0);
        __syncthreads();
        *(uint4*)&Al[sa_row][sa_half]     = a0;
        *(uint4*)&Al[sa_row][sa_half + 8] = a1;
        *(uint4*)&Bl[sb_row][sb_q]        = b0;
        __syncthreads();
        bf8 a[4], b[2];
        #pragma unroll
        for (int mi = 0; mi < 4; ++mi) a[mi] = *(const bf8*)&Al[wr * 64 + mi * 16 + lr][g * 8];
        #pragma unroll
        for (int ni = 0; ni < 2; ++ni) b[ni] = *(const bf8*)&Bl[wc * 32 + ni * 16 + lr][g * 8];
        #pragma unroll
        for (int mi = 0; mi < 4; ++mi)
            #pragma unroll
            for (int ni = 0; ni < 2; ++ni)
                acc[mi][ni] = __builtin_amdgcn_mfma_f32_16x16x32_bf16(a[mi], b[ni], acc[mi][ni], 0, 0, 0);
    }
    #pragma unroll
    for (int mi = 0; mi < 4; ++mi) {
        const int m0 = row0 + wr * 64 + mi * 16 + g * 4;
        #pragma unroll
        for (int ni = 0; ni < 2; ++ni) {
            const int n = col0 + wc * 32 + ni * 16 + lr;
            #pragma unroll
            for (int r = 0; r < 4; ++r)
                Cp[(size_t)(m0 + r) * DM + n] = acc[mi][ni][r];
        }
    }
}

// -------- nrw + fused scan-pre --------
__global__ __launch_bounds__(256) void nrw_kernel(
    const float* __restrict__ qraw, const float* __restrict__ kraw,
    const float* __restrict__ Amat, float* __restrict__ gateq,
    ushort* __restrict__ kgb,
    float* __restrict__ kcoefA, float* __restrict__ R0A,
    float* __restrict__ R1A, float* __restrict__ r15A)
{
    __shared__ float S[64][64];
    __shared__ float zq[4][64];
    __shared__ float zk[4][64];
    const int bh = blockIdx.x;
    const int h = bh & (NH - 1);
    const int tid = threadIdx.x;
    const int g = tid >> 6, lane = tid & 63;
    for (int idx = tid; idx < 4096; idx += 256) {
        const int d = idx >> 6, e = idx & 63;
        S[d][e] = Amat[(size_t)h * 4096 + d * 64 + e] - Amat[(size_t)h * 4096 + e * 64 + d];
    }
    __syncthreads();
    const int j = lane & 31;
    const float invf = powf(10000.0f, -(float)(2 * j) * (1.0f / 64.0f));
    const int t0 = blockIdx.y * 64 + g * 16;
    float kc0 = 0.f, kc1 = 0.f, run = 0.f, Ra0 = 0.f, Ra1 = 0.f;
    for (int r = 0; r < 16; ++r) {
        const int t = t0 + r;
        const size_t base = ((size_t)bh * NT + t) * DH;
        const float qv = qraw[base + lane];
        const float kv = kraw[base + lane];
        float sq = qv, sk = kv, qq = qv * qv, kk2 = kv * kv;
        #pragma unroll
        for (int off = 32; off; off >>= 1) {
            sq += __shfl_xor(sq, off);
            sk += __shfl_xor(sk, off);
            qq += __shfl_xor(qq, off);
            kk2 += __shfl_xor(kk2, off);
        }
        const float mq = sq * (1.0f / 64.0f), mk = sk * (1.0f / 64.0f);
        const float vq = (qq - 64.0f * mq * mq) * (1.0f / 63.0f);
        const float vk = (kk2 - 64.0f * mk * mk) * (1.0f / 63.0f);
        const float ms = 0.5f * (mq + mk);
        const float ss = 0.5f * (sqrtf(fmaxf(vq, 0.0f)) + sqrtf(fmaxf(vk, 0.0f)));
        const float rinv = 1.0f / (ss + 1e-6f);
        const float qn = (qv - ms) * rinv;
        const float kn = (kv - ms) * rinv;
        const float q1 = __shfl(qn, 2 * j), q2 = __shfl(qn, 2 * j + 1);
        const float k1 = __shfl(kn, 2 * j), k2 = __shfl(kn, 2 * j + 1);
        float sn, cs;
        sincosf((float)t * invf, &sn, &cs);
        const float rq = (lane < 32) ? (q1 * cs - q2 * sn) : (q1 * sn + q2 * cs);
        const float rk = (lane < 32) ? (k1 * cs - k2 * sn) : (k1 * sn + k2 * cs);
        zq[g][lane] = rq;
        zk[g][lane] = rk;
        float aq = 0.0f, ak = 0.0f;
        #pragma unroll 8
        for (int d = 0; d < 64; ++d) {
            const float sde = S[d][lane];
            aq = fmaf(zq[g][d], sde, aq);
            ak = fmaf(zk[g][d], sde, ak);
        }
        const float qgv = rq + aq;
        const float kgv = rk + ak;
        const float gv = gateq[base + lane];
        const float qgpv = gv * qgv;
        gateq[base + lane] = qgpv;
        kgb[base + lane] = f2bf(kgv);
        kc0 = fmaf(kgv, 0.25f, kc0);
        kc1 = fmaf(kgv, wbf(r, 1), kc1);
        run += qgpv;
        Ra0 = fmaf(run, 0.25f, Ra0);
        Ra1 = fmaf(run, wbf(r, 1), Ra1);
    }
    const int unit = bh * 128 + blockIdx.y * 4 + g;
    kcoefA[(size_t)unit * 128 + lane] = kc0;
    kcoefA[(size_t)unit * 128 + 64 + lane] = kc1;
    R0A[(size_t)unit * 64 + lane] = Ra0;
    R1A[(size_t)unit * 64 + lane] = Ra1;
    r15A[(size_t)unit * 64 + lane] = run;
}

// -------- merged: blocks 0..31 serial scan (4-wave batch phases, wave-0 serial inner);
//          blocks 32+ V-projection GEMM --------
__global__ __launch_bounds__(256) void scan_vgemm_kernel(
    const float* __restrict__ kcoefA, const float* __restrict__ R0A,
    const float* __restrict__ R1A, const float* __restrict__ r15A,
    const float* __restrict__ jscale, const float* __restrict__ jbias,
    float* __restrict__ r0O, float* __restrict__ r1O,
    float* __restrict__ lpO, float* __restrict__ jgO,
    const ushort* __restrict__ xb, const ushort* __restrict__ Wb,
    ushort* __restrict__ Vt)
{
    __shared__ char smem[100864];
    if (blockIdx.x >= 32) {
        const int gi = blockIdx.x - 32;
        const int col0 = (gi & 15) * 64;
        const int row0 = (gi >> 4) * 128;
        ushort (*Al)[40] = (ushort(*)[40])smem;
        ushort (*Bl)[40] = (ushort(*)[40])(smem + 10240);
        const int tid = threadIdx.x;
        const int l = tid & 63, w = tid >> 6;
        const int wr = w >> 1, wc = w & 1;
        const int lr = l & 15, g = l >> 4;
        f32x4 acc[4][2];
        #pragma unroll
        for (int mi = 0; mi < 4; ++mi)
            #pragma unroll
            for (int ni = 0; ni < 2; ++ni) acc[mi][ni] = (f32x4){0.f, 0.f, 0.f, 0.f};
        const int sa_row = tid >> 1, sa_half = (tid & 1) * 16;
        const int sb_row = tid >> 2, sb_q = (tid & 3) * 8;
        const ushort* Ap = xb + (size_t)(row0 + sa_row) * DM + sa_half;
        const ushort* Bp = Wb + (size_t)(col0 + sb_row) * DM + sb_q;
        for (int k0 = 0; k0 < DM; k0 += 32) {
            const uint4 a0 = *(const uint4*)(Ap + k0);
            const uint4 a1 = *(const uint4*)(Ap + k0 + 8);
            const uint4 b0 = *(const uint4*)(Bp + k0);
            __syncthreads();
            *(uint4*)&Al[sa_row][sa_half]     = a0;
            *(uint4*)&Al[sa_row][sa_half + 8] = a1;
            *(uint4*)&Bl[sb_row][sb_q]        = b0;
            __syncthreads();
            bf8 a[4], b[2];
            #pragma unroll
            for (int mi = 0; mi < 4; ++mi) a[mi] = *(const bf8*)&Al[wr * 64 + mi * 16 + lr][g * 8];
            #pragma unroll
            for (int ni = 0; ni < 2; ++ni) b[ni] = *(const bf8*)&Bl[wc * 32 + ni * 16 + lr][g * 8];
            #pragma unroll
            for (int mi = 0; mi < 4; ++mi)
                #pragma unroll
                for (int ni = 0; ni < 2; ++ni)
                    acc[mi][ni] = __builtin_amdgcn_mfma_f32_16x16x32_bf16(a[mi], b[ni], acc[mi][ni], 0, 0, 0);
        }
        #pragma unroll
        for (int mi = 0; mi < 4; ++mi) {
            const int m0 = row0 + wr * 64 + mi * 16 + g * 4;
            const int bb = m0 >> 11, t0 = m0 & 2047;
            #pragma unroll
            for (int ni = 0; ni < 2; ++ni) {
                const int n = col0 + wc * 32 + ni * 16 + lr;
                const int h = n >> 6, dh = n & 63;
                ushort4 pk;
                pk.x = f2bf(acc[mi][ni][0]); pk.y = f2bf(acc[mi][ni][1]);
                pk.z = f2bf(acc[mi][ni][2]); pk.w = f2bf(acc[mi][ni][3]);
                *(ushort4*)(Vt + (((size_t)(bb * NH + h)) * DH + dh) * NT + t0) = pk;
            }
        }
        return;
    }
    // ---- serial scan: 4-wave batch phases, wave-0 serial inner ----
    float* HA  = (float*)smem;
    float* KcL = (float*)(smem + 65536);
    float* EL  = (float*)(smem + 73728);
    float* ET  = (float*)(smem + 82176);
    float* VP  = (float*)(smem + 92416);
    float* mxold = (float*)(smem + 100608);
    float* psold = (float*)(smem + 100672);
    float* pbuf  = (float*)(smem + 100736);
    float* qbuf    = (float*)(smem + 73728);   // aliases EL (dead during serial inner)
    float* candBuf = (float*)(smem + 74752);
    const int bh = blockIdx.x;
    const int tid = threadIdx.x;
    const int l = tid & 63, w = tid >> 6;
    #pragma unroll
    for (int c = 0; c < 16; ++c)
        *(f32x4*)&HA[c * 1024 + tid * 4] = (f32x4){0.f, 0.f, 0.f, 0.f};
    const float js = jscale[0], jb = jbias[0];
    const float* kcp  = kcoefA + (size_t)bh * 128 * 128;
    const float* R0p  = R0A  + (size_t)bh * 128 * 64;
    const float* R1p  = R1A  + (size_t)bh * 128 * 64;
    const float* r15p = r15A + (size_t)bh * 128 * 64;
    float* r0o = r0O + (size_t)bh * 128 * 64;
    float* r1o = r1O + (size_t)bh * 128 * 64;
    float* lpo = lpO + (size_t)bh * 128 * 64;
    float* jgo = jgO + (size_t)bh * 128;
    float last = 0.0f;
    const float wb15_1 = wbf(15, 1);
    const int iiq = l >> 2, sq = l & 3;
    const int ch = l >> 2;

    for (int j = 0; j < 8; ++j) {
        const int P = 16 * j;
        // KcL load: 256 threads, 8 floats each
        *(f32x4*)&KcL[tid * 8]     = *(const f32x4*)&kcp[j * 2048 + tid * 8];
        *(f32x4*)&KcL[tid * 8 + 4] = *(const f32x4*)&kcp[j * 2048 + tid * 8 + 4];
        float R0b[16], R1b[16], r15b[16];
        if (w == 0) {
            #pragma unroll
            for (int t = 0; t < 16; ++t) {
                R0b[t]  = R0p[(P + t) * 64 + l];
                R1b[t]  = R1p[(P + t) * 64 + l];
                r15b[t] = r15p[(P + t) * 64 + l];
            }
        }
        __syncthreads();   // KcL + prev-j HA visible
        // --- SC_old split: wave w owns ii = 4w..4w+3; lane owns rows l, 64+l ---
        {
            float sA[4] = {0.f, 0.f, 0.f, 0.f};
            float sB[4] = {0.f, 0.f, 0.f, 0.f};
            const int swA = l & 31;
            for (int c = 0; c < 32; ++c) {
                const int cs = ((c ^ swA) << 2);
                const f32x4 hA = *(const f32x4*)&HA[l * 128 + cs];
                const f32x4 hB = *(const f32x4*)&HA[(64 + l) * 128 + cs];
                #pragma unroll
                for (int t = 0; t < 4; ++t) {
                    const f32x4 kc = *(const f32x4*)&KcL[(4 * w + t) * 128 + (c << 2)];
                    sA[t] = fmaf(hA[0], kc[0], sA[t]); sA[t] = fmaf(hA[1], kc[1], sA[t]);
                    sA[t] = fmaf(hA[2], kc[2], sA[t]); sA[t] = fmaf(hA[3], kc[3], sA[t]);
                    sB[t] = fmaf(hB[0], kc[0], sB[t]); sB[t] = fmaf(hB[1], kc[1], sB[t]);
                    sB[t] = fmaf(hB[2], kc[2], sB[t]); sB[t] = fmaf(hB[3], kc[3], sB[t]);
                }
            }
            #pragma unroll
            for (int t = 0; t < 4; ++t) {
                if (l < P)      EL[(4 * w + t) * 132 + l]      = sA[t] * 0.125f;
                if (64 + l < P) EL[(4 * w + t) * 132 + 64 + l] = sB[t] * 0.125f;
            }
        }
        __syncthreads();   // EL visible
        // --- mxold / E / ET / psold: wave 0 (verbatim) ---
        if (w == 0) {
            float m = -1e30f;
            for (int n = sq; n < P; n += 4) m = fmaxf(m, EL[iiq * 132 + n]);
            m = fmaxf(m, __shfl_xor(m, 1));
            m = fmaxf(m, __shfl_xor(m, 2));
            if (sq == 0) mxold[iiq] = m;
            const float mo = (P > 0) ? m : -1e30f;
            float ps = 0.f;
            for (int n = sq; n < P; n += 4) {
                const float e = __expf(EL[iiq * 132 + n] - mo);
                ET[n * 20 + iiq] = e;
                ps += e;
            }
            ps += __shfl_xor(ps, 1);
            ps += __shfl_xor(ps, 2);
            if (sq == 0) psold[iiq] = ps;
        }
        __syncthreads();   // ET/mxold/psold visible
        // --- VP split: wave w owns ii = 4w..4w+3; lane owns kd = l, 64+l ---
        {
            float vp0[4] = {0.f, 0.f, 0.f, 0.f};
            float vp1[4] = {0.f, 0.f, 0.f, 0.f};
            for (int n = 0; n < P; ++n) {
                const int sw = n & 31;
                const float h0 = HA[n * 128 + ((ch ^ sw) << 2) + (l & 3)];
                const float h1 = HA[n * 128 + (((16 + ch) ^ sw) << 2) + (l & 3)];
                const f32x4 e = *(const f32x4*)&ET[n * 20 + 4 * w];
                #pragma unroll
                for (int u = 0; u < 4; ++u) {
                    vp0[u] = fmaf(e[u], h0, vp0[u]);
                    vp1[u] = fmaf(e[u], h1, vp1[u]);
                }
            }
            #pragma unroll
            for (int u = 0; u < 4; ++u) {
                VP[(4 * w + u) * 128 + l]      = vp0[u];
                VP[(4 * w + u) * 128 + 64 + l] = vp1[u];
            }
        }
        __syncthreads();   // VP visible to wave 0
        // --- serial inner: wave 0 only (r22 verbatim) ---
        if (w == 0) {
            const int n_ = l >> 2, q = l & 3;
            const int qb = l & ~3;
            #pragma unroll
            for (int iL = 0; iL < 16; ++iL) {
                const int i = P + iL;
                const int nrow = P + n_;
                const int nsw = nrow & 31;
                float scp = 0.f;
                #pragma unroll
                for (int c = 0; c < 8; ++c) {
                    const f32x4 h  = *(const f32x4*)&HA[nrow * 128 + ((((q << 3) + c) ^ nsw) << 2)];
                    const f32x4 kc = *(const f32x4*)&KcL[iL * 128 + (q << 5) + (c << 2)];
                    scp = fmaf(h[0], kc[0], scp); scp = fmaf(h[1], kc[1], scp);
                    scp = fmaf(h[2], kc[2], scp); scp = fmaf(h[3], kc[3], scp);
                }
                qbuf[l] = scp;
                const float scn = (qbuf[qb] + qbuf[qb + 1]) + (qbuf[qb + 2] + qbuf[qb + 3]);
                const float cand = (n_ < iL) ? scn * 0.125f : -1e30f;
                if (q == 0) candBuf[n_] = cand;
                float m8[8];
                #pragma unroll
                for (int u = 0; u < 8; ++u) m8[u] = fmaxf(candBuf[2 * u], candBuf[2 * u + 1]);
                float m4a = fmaxf(m8[0], m8[1]), m4b = fmaxf(m8[2], m8[3]);
                float m4c = fmaxf(m8[4], m8[5]), m4d = fmaxf(m8[6], m8[7]);
                const float mxn = fmaxf(fmaxf(m4a, m4b), fmaxf(m4c, m4d));
                const float mo = mxold[iL];
                const float mx = fmaxf(mxn, mo);
                const float p = (n_ < iL) ? __expf(cand - mx) : 0.f;
                if (q == 0) pbuf[n_] = p;
                float s8[8];
                #pragma unroll
                for (int u = 0; u < 8; ++u) s8[u] = pbuf[2 * u] + pbuf[2 * u + 1];
                float s4a = s8[0] + s8[1], s4b = s8[2] + s8[3];
                float s4c = s8[4] + s8[5], s4d = s8[6] + s8[7];
                const float psn = (s4a + s4b) + (s4c + s4d);
                float r0 = 0.f, r1 = 0.f;
                if (i > 0) {
                    const float so = __expf(mo - mx);
                    float racc0 = VP[iL * 128 + l] * so;
                    float racc1 = VP[iL * 128 + 64 + l] * so;
                    #pragma unroll
                    for (int n2 = 0; n2 < iL; ++n2) {
                        const float pn = pbuf[n2];
                        const int nr = P + n2;
                        const int sw2 = nr & 31;
                        racc0 = fmaf(pn, HA[nr * 128 + ((ch ^ sw2) << 2) + (l & 3)], racc0);
                        racc1 = fmaf(pn, HA[nr * 128 + (((16 + ch) ^ sw2) << 2) + (l & 3)], racc1);
                    }
                    const float ps = fmaf(psold[iL], so, psn);
                    const float rden = 1.0f / ps;
                    r0 = racc0 * rden;
                    r1 = racc1 * rden;
                }
                const float jg = 1.0f / (1.0f + __expf(-fmaf(mx, js, jb)));
                const float lastp = last;
                const float h0n = R0b[iL] + fmaf(jg, r0, 4.0f * (1.0f - jg) * lastp);
                const float h1n = fmaf(jg, r1, R1b[iL]);
                const float qrec15 = fmaf(r0, 0.25f, r1 * wb15_1);
                last = r15b[iL] + fmaf(jg, qrec15, (1.0f - jg) * lastp);
                r0o[i * 64 + l] = r0;
                r1o[i * 64 + l] = r1;
                lpo[i * 64 + l] = lastp;
                if (l == 0) jgo[i] = jg;
                const int swi = i & 31;
                HA[i * 128 + ((ch ^ swi) << 2) + (l & 3)] = h0n;
                HA[i * 128 + (((16 + ch) ^ swi) << 2) + (l & 3)] = h1n;
            }
        }
        __syncthreads();   // serial HA writes visible for next j
    }
}

// -------- scan post-pass: Qout = cumsum(qgp) + inj --------
__global__ __launch_bounds__(256) void scan_post_kernel(
    const float* __restrict__ qgp, const float* __restrict__ r0O,
    const float* __restrict__ r1O, const float* __restrict__ lpO,
    const float* __restrict__ jgO, float* __restrict__ Qout)
{
    const int unit = blockIdx.x * 4 + (threadIdx.x >> 6);
    const int d = threadIdx.x & 63;
    const int bh = unit >> 7, i = unit & 127;
    const size_t ub = (size_t)unit * 64 + d;
    const float r0 = r0O[ub], r1 = r1O[ub], lp = lpO[ub];
    const float jg = jgO[unit];
    const size_t cbase = ((size_t)bh * NT + i * 16) * DH + d;
    float run = 0.0f;
    #pragma unroll
    for (int ll = 0; ll < 16; ++ll) {
        run += qgp[cbase + ll * 64];
        const float qrec = fmaf(r0, 0.25f, r1 * wbf(ll, 1));
        const float inj = (i > 0) ? fmaf(jg, qrec, (1.0f - jg) * lp) : 0.0f;
        Qout[cbase + ll * 64] = run + inj;
    }
}

// -------- MFMA flash attention v2: KVBLK=64, split [40]-stride LDS, per-lane lrow --------
__global__ __launch_bounds__(256) void attn_mfma_kernel(
    const float* __restrict__ Qf, const ushort* __restrict__ Kb,
    const ushort* __restrict__ Vtb, const float* __restrict__ sink,
    const float* __restrict__ vnull, ushort* __restrict__ Ob)
{
    __shared__ ushort Kl0[64][40], Kl1[64][40];
    __shared__ ushort Vl0[64][40], Vl1[64][40];
    __shared__ ushort Pl[4][2][16][40];
    const int bh = blockIdx.y;
    const int h = bh & (NH - 1);
    const int b = bh >> 4;
    const int qt = gridDim.x - 1 - blockIdx.x;
    const int q0 = qt * 64;
    const int tid = threadIdx.x;
    const int w = tid >> 6, l = tid & 63;
    const int lr = l & 15, g = l >> 4;
    bf8 qf[2];
    {
        const float* qp = Qf + (((size_t)bh * NT) + q0 + 16 * w + lr) * DH + g * 8;
        #pragma unroll
        for (int ks = 0; ks < 2; ++ks) {
            const float4 f0 = *(const float4*)(qp + 32 * ks);
            const float4 f1 = *(const float4*)(qp + 32 * ks + 4);
            bf8 q;
            q[0] = (short)f2bf(f0.x); q[1] = (short)f2bf(f0.y);
            q[2] = (short)f2bf(f0.z); q[3] = (short)f2bf(f0.w);
            q[4] = (short)f2bf(f1.x); q[5] = (short)f2bf(f1.y);
            q[6] = (short)f2bf(f1.z); q[7] = (short)f2bf(f1.w);
            qf[ks] = q;
        }
    }
    f32x4 oacc[4];
    #pragma unroll
    for (int nf2 = 0; nf2 < 4; ++nf2) oacc[nf2] = (f32x4){0.f, 0.f, 0.f, 0.f};
    float mrow[4], lrowp[4];
    #pragma unroll
    for (int r = 0; r < 4; ++r) { mrow[r] = -1e30f; lrowp[r] = 0.0f; }
    const int ntiles = qt + 1;
    const ushort* Kg = Kb + (size_t)bh * NT * DH;
    const ushort* Vg = Vtb + (size_t)bh * DH * NT;
    const int srow = tid >> 2;
    const int sc16 = (tid & 3) * 16;
    for (int it = 0; it < ntiles; ++it) {
        const int kv0 = it * 64;
        __syncthreads();
        {
            const ushort* kp = Kg + (size_t)(kv0 + srow) * DH + sc16;
            const ushort* vp = Vg + (size_t)srow * NT + kv0 + sc16;
            ushort* kd = (sc16 < 32) ? &Kl0[srow][sc16] : &Kl1[srow][sc16 - 32];
            ushort* vd = (sc16 < 32) ? &Vl0[srow][sc16] : &Vl1[srow][sc16 - 32];
            *(uint4*)kd       = *(const uint4*)kp;
            *(uint4*)(kd + 8) = *(const uint4*)(kp + 8);
            *(uint4*)vd       = *(const uint4*)vp;
            *(uint4*)(vd + 8) = *(const uint4*)(vp + 8);
        }
        __syncthreads();
        f32x4 s[4];
        #pragma unroll
        for (int nf = 0; nf < 4; ++nf) {
            s[nf] = (f32x4){0.f, 0.f, 0.f, 0.f};
            const bf8 kf0 = *(const bf8*)&Kl0[nf * 16 + lr][g * 8];
            const bf8 kf1 = *(const bf8*)&Kl1[nf * 16 + lr][g * 8];
            s[nf] = __builtin_amdgcn_mfma_f32_16x16x32_bf16(qf[0], kf0, s[nf], 0, 0, 0);
            s[nf] = __builtin_amdgcn_mfma_f32_16x16x32_bf16(qf[1], kf1, s[nf], 0, 0, 0);
        }
        #pragma unroll
        for (int r = 0; r < 4; ++r) {
            const int row = q0 + 16 * w + g * 4 + r;
            float sv[4];
            float tmax = -1e30f;
            #pragma unroll
            for (int nf = 0; nf < 4; ++nf) {
                const int col = kv0 + nf * 16 + lr;
                sv[nf] = (col <= row) ? s[nf][r] * 0.125f : -1e30f;
                tmax = fmaxf(tmax, sv[nf]);
            }
            tmax = fmaxf(tmax, __shfl_xor(tmax, 1));
            tmax = fmaxf(tmax, __shfl_xor(tmax, 2));
            tmax = fmaxf(tmax, __shfl_xor(tmax, 4));
            tmax = fmaxf(tmax, __shfl_xor(tmax, 8));
            const float mnew = fmaxf(mrow[r], tmax);
            const float csc = __expf(mrow[r] - mnew);
            float plocal = 0.f;
            #pragma unroll
            for (int nf = 0; nf < 4; ++nf) {
                const float p = __expf(sv[nf] - mnew);
                plocal += p;
                Pl[w][nf >> 1][g * 4 + r][(nf & 1) * 16 + lr] = f2bf(p);
            }
            lrowp[r] = lrowp[r] * csc + plocal;
            mrow[r] = mnew;
            #pragma unroll
            for (int nf2 = 0; nf2 < 4; ++nf2) oacc[nf2][r] *= csc;
        }
        const bf8 pa0 = *(const bf8*)&Pl[w][0][lr][g * 8];
        const bf8 pa1 = *(const bf8*)&Pl[w][1][lr][g * 8];
        #pragma unroll
        for (int nf2 = 0; nf2 < 4; ++nf2) {
            const bf8 vb0 = *(const bf8*)&Vl0[nf2 * 16 + lr][g * 8];
            const bf8 vb1 = *(const bf8*)&Vl1[nf2 * 16 + lr][g * 8];
            oacc[nf2] = __builtin_amdgcn_mfma_f32_16x16x32_bf16(pa0, vb0, oacc[nf2], 0, 0, 0);
            oacc[nf2] = __builtin_amdgcn_mfma_f32_16x16x32_bf16(pa1, vb1, oacc[nf2], 0, 0, 0);
        }
    }
    float lrow[4];
    #pragma unroll
    for (int r = 0; r < 4; ++r) {
        float ps = lrowp[r];
        ps += __shfl_xor(ps, 1);
        ps += __shfl_xor(ps, 2);
        ps += __shfl_xor(ps, 4);
        ps += __shfl_xor(ps, 8);
        lrow[r] = ps;
    }
    const float s0 = sink[h];
    float c0v[4], pnv[4], rden[4];
    #pragma unroll
    for (int r = 0; r < 4; ++r) {
        const float mf = fmaxf(mrow[r], s0);
        c0v[r] = __expf(mrow[r] - mf);
        pnv[r] = __expf(s0 - mf);
        rden[r] = 1.0f / fmaf(lrow[r], c0v[r], pnv[r]);
    }
    #pragma unroll
    for (int nf2 = 0; nf2 < 4; ++nf2) {
        const float vn = vnull[h * DH + nf2 * 16 + lr];
        #pragma unroll
        for (int r = 0; r < 4; ++r) {
            const float out = fmaf(pnv[r], vn, oacc[nf2][r] * c0v[r]) * rden[r];
            const int trow = q0 + 16 * w + g * 4 + r;
            Ob[(((size_t)b * NT) + trow) * DM + h * DH + nf2 * 16 + lr] = f2bf(out);
        }
    }
}

extern "C" void kernel_launch(void* const* d_in, const int* in_sizes, int n_in,
                              void* d_out, int out_size, void* d_ws, size_t ws_size,
                              hipStream_t stream) {
    const float* x     = (const float*)d_in[0];
    const float* Wq    = (const float*)d_in[1];
    const float* Wk    = (const float*)d_in[2];
    const float* Wv    = (const float*)d_in[3];
    const float* Wo    = (const float*)d_in[4];
    const float* gw    = (const float*)d_in[5];
    const float* gbias = (const float*)d_in[6];
    const float* Amat  = (const float*)d_in[7];
    const float* js    = (const float*)d_in[8];
    const float* jb    = (const float*)d_in[9];
    const float* sink  = (const float*)d_in[10];
    const float* vnull = (const float*)d_in[11];
    char* ws = (char*)d_ws;
    const size_t MB = 1024 * 1024;
    float*  q_raw  = (float*)(ws + 0);
    float*  k_raw  = (float*)(ws + 16 * MB);
    float*  gate   = (float*)(ws + 32 * MB);
    ushort* kgb    = (ushort*)(ws + 64 * MB);
    ushort* xb     = (ushort*)(ws + 72 * MB);
    ushort* Wb     = (ushort*)(ws + 80 * MB);
    float*  kcoefA = (float*)(ws + 84 * MB);
    float*  R0A    = (float*)(ws + 86 * MB);
    float*  R1A    = (float*)(ws + 87 * MB);
    float*  r15A   = (float*)(ws + 88 * MB);
    float*  r0O    = (float*)(ws + 89 * MB);
    float*  r1O    = (float*)(ws + 90 * MB);
    float*  lpO    = (float*)(ws + 91 * MB);
    float*  jgO    = (float*)(ws + 92 * MB);
    ushort* Vt     = (ushort*)k_raw;
    ushort* attob  = (ushort*)(ws + 24 * MB);

    cast3_kernel<<<6144, 256, 0, stream>>>(x, Wv, Wo, xb, Wb);
    gemm3m_kernel<<<dim3(DM / 64, (NB * NT) / 128, 3), 256, 0, stream>>>(
        x, Wq, Wk, gw, gbias, q_raw, k_raw, gate);
    nrw_kernel<<<dim3(NB * NH, NT / 64), 256, 0, stream>>>(
        q_raw, k_raw, Amat, gate, kgb, kcoefA, R0A, R1A, r15A);
    scan_vgemm_kernel<<<32 + 512, 256, 0, stream>>>(
        kcoefA, R0A, R1A, r15A, js, jb, r0O, r1O, lpO, jgO, xb, Wb, Vt);
    scan_post_kernel<<<1024, 256, 0, stream>>>(gate, r0O, r1O, lpO, jgO, q_raw);
    attn_mfma_kernel<<<dim3(NT / 64, NB * NH), 256, 0, stream>>>(q_raw, kgb, Vt, sink, vnull, attob);
    gemm_bf16_kernel<<<dim3(DM / 64, (NB * NT) / 128), 256, 0, stream>>>(
        attob, Wb + DM * DM, (float*)d_out);
}

// Round 24
// 663.986 us; speedup vs baseline: 1.2276x; 1.2276x over previous
//
#include <hip/hip_runtime.h>
#include <math.h>

#define NB 2
#define NT 2048
#define NH 16
#define DH 64
#define DM 1024

using bf8   = __attribute__((ext_vector_type(8))) short;
using f32x4 = __attribute__((ext_vector_type(4))) float;

static __device__ __forceinline__ ushort f2bf(float f) {
    union { float f; unsigned u; } c; c.f = f;
    unsigned u = c.u + 0x7FFFu + ((c.u >> 16) & 1u);
    return (ushort)(u >> 16);
}
static __device__ __forceinline__ float bf2f(ushort u) {
    union { unsigned u; float f; } c; c.u = ((unsigned)u) << 16;
    return c.f;
}

// Alpert basis W_b (CHUNK=16, K=2): col0 = 1/4, col1 = t/||t||, t=linspace(-1,1,16)
static __device__ __forceinline__ float wbf(int l, int k) {
    if (k == 0) return 0.25f;
    const float invn = 1.0f / sqrtf(1360.0f / 225.0f);
    return (-1.0f + (2.0f / 15.0f) * (float)l) * invn;
}

// ---------- cast x, Wv, Wo to bf16 ----------
__global__ __launch_bounds__(256) void cast3_kernel(
    const float* __restrict__ x, const float* __restrict__ wv,
    const float* __restrict__ wo, ushort* __restrict__ xb, ushort* __restrict__ wb)
{
    const int id = blockIdx.x * 256 + threadIdx.x;
    const int XQ = (NB * NT * DM) / 4;
    const int WQ = (DM * DM) / 4;
    const float4* src;
    ushort* dst;
    if (id < XQ) {
        src = (const float4*)x + id;
        dst = xb + (size_t)id * 4;
    } else {
        const int r = id - XQ;
        const int wi = r / WQ, off = r % WQ;
        const float* w = (wi == 0) ? wv : wo;
        src = (const float4*)w + off;
        dst = wb + (size_t)wi * DM * DM + (size_t)off * 4;
    }
    const float4 v = *src;
    ushort4 o;
    o.x = f2bf(v.x); o.y = f2bf(v.y); o.z = f2bf(v.z); o.w = f2bf(v.w);
    *(ushort4*)dst = o;
}

// ---------- q/k/gate projections via bf16x3 MFMA emulation (6 products, fp32-level accuracy) ----------
__global__ __launch_bounds__(256) void gemm3m_kernel(
    const float* __restrict__ x, const float* __restrict__ Wq,
    const float* __restrict__ Wk, const float* __restrict__ gw,
    const float* __restrict__ gbias,
    float* __restrict__ oq, float* __restrict__ ok, float* __restrict__ og)
{
    __shared__ ushort Ah[128][40], Am[128][40], Al[128][40];
    __shared__ ushort Bh[64][40],  Bm[64][40],  Bl[64][40];
    const int z = blockIdx.z;
    const float* Bw = (z == 0) ? Wq : (z == 1) ? Wk : gw;
    float* C = (z == 0) ? oq : (z == 1) ? ok : og;
    const int tid = threadIdx.x;
    const int l = tid & 63, w = tid >> 6;
    const int wr = w >> 1, wc = w & 1;
    const int lr = l & 15, g = l >> 4;
    const int row0 = blockIdx.y * 128, col0 = blockIdx.x * 64;
    f32x4 acc[4][2];
    #pragma unroll
    for (int mi = 0; mi < 4; ++mi)
        #pragma unroll
        for (int ni = 0; ni < 2; ++ni) acc[mi][ni] = (f32x4){0.f, 0.f, 0.f, 0.f};
    const int sa_row = tid >> 1, sa_col = (tid & 1) * 16;
    const int sb_row = tid >> 2, sb_col = (tid & 3) * 8;
    const float* Ap = x  + (size_t)(row0 + sa_row) * DM + sa_col;
    const float* Bp = Bw + (size_t)(col0 + sb_row) * DM + sb_col;
    for (int k0 = 0; k0 < DM; k0 += 32) {
        float av[16], bv[8];
        *(float4*)&av[0]  = *(const float4*)(Ap + k0);
        *(float4*)&av[4]  = *(const float4*)(Ap + k0 + 4);
        *(float4*)&av[8]  = *(const float4*)(Ap + k0 + 8);
        *(float4*)&av[12] = *(const float4*)(Ap + k0 + 12);
        *(float4*)&bv[0]  = *(const float4*)(Bp + k0);
        *(float4*)&bv[4]  = *(const float4*)(Bp + k0 + 4);
        __syncthreads();
        #pragma unroll
        for (int c = 0; c < 16; c += 4) {
            ushort4 hh, mm, ll;
            ushort* hp = (ushort*)&hh;
            ushort* mp = (ushort*)&mm;
            ushort* lp = (ushort*)&ll;
            #pragma unroll
            for (int u = 0; u < 4; ++u) {
                const float v = av[c + u];
                const ushort hu = f2bf(v);
                const float r1 = v - bf2f(hu);
                const ushort mu = f2bf(r1);
                const ushort lu = f2bf(r1 - bf2f(mu));
                hp[u] = hu; mp[u] = mu; lp[u] = lu;
            }
            *(ushort4*)&Ah[sa_row][sa_col + c] = hh;
            *(ushort4*)&Am[sa_row][sa_col + c] = mm;
            *(ushort4*)&Al[sa_row][sa_col + c] = ll;
        }
        #pragma unroll
        for (int c = 0; c < 8; c += 4) {
            ushort4 hh, mm, ll;
            ushort* hp = (ushort*)&hh;
            ushort* mp = (ushort*)&mm;
            ushort* lp = (ushort*)&ll;
            #pragma unroll
            for (int u = 0; u < 4; ++u) {
                const float v = bv[c + u];
                const ushort hu = f2bf(v);
                const float r1 = v - bf2f(hu);
                const ushort mu = f2bf(r1);
                const ushort lu = f2bf(r1 - bf2f(mu));
                hp[u] = hu; mp[u] = mu; lp[u] = lu;
            }
            *(ushort4*)&Bh[sb_row][sb_col + c] = hh;
            *(ushort4*)&Bm[sb_row][sb_col + c] = mm;
            *(ushort4*)&Bl[sb_row][sb_col + c] = ll;
        }
        __syncthreads();
        bf8 ah[4], am[4], al[4], bh[2], bm[2], bl[2];
        #pragma unroll
        for (int mi = 0; mi < 4; ++mi) {
            ah[mi] = *(const bf8*)&Ah[wr * 64 + mi * 16 + lr][g * 8];
            am[mi] = *(const bf8*)&Am[wr * 64 + mi * 16 + lr][g * 8];
            al[mi] = *(const bf8*)&Al[wr * 64 + mi * 16 + lr][g * 8];
        }
        #pragma unroll
        for (int ni = 0; ni < 2; ++ni) {
            bh[ni] = *(const bf8*)&Bh[wc * 32 + ni * 16 + lr][g * 8];
            bm[ni] = *(const bf8*)&Bm[wc * 32 + ni * 16 + lr][g * 8];
            bl[ni] = *(const bf8*)&Bl[wc * 32 + ni * 16 + lr][g * 8];
        }
        #pragma unroll
        for (int mi = 0; mi < 4; ++mi)
            #pragma unroll
            for (int ni = 0; ni < 2; ++ni) {
                acc[mi][ni] = __builtin_amdgcn_mfma_f32_16x16x32_bf16(ah[mi], bh[ni], acc[mi][ni], 0, 0, 0);
                acc[mi][ni] = __builtin_amdgcn_mfma_f32_16x16x32_bf16(ah[mi], bm[ni], acc[mi][ni], 0, 0, 0);
                acc[mi][ni] = __builtin_amdgcn_mfma_f32_16x16x32_bf16(am[mi], bh[ni], acc[mi][ni], 0, 0, 0);
                acc[mi][ni] = __builtin_amdgcn_mfma_f32_16x16x32_bf16(am[mi], bm[ni], acc[mi][ni], 0, 0, 0);
                acc[mi][ni] = __builtin_amdgcn_mfma_f32_16x16x32_bf16(ah[mi], bl[ni], acc[mi][ni], 0, 0, 0);
                acc[mi][ni] = __builtin_amdgcn_mfma_f32_16x16x32_bf16(al[mi], bh[ni], acc[mi][ni], 0, 0, 0);
            }
    }
    #pragma unroll
    for (int mi = 0; mi < 4; ++mi) {
        const int m0 = row0 + wr * 64 + mi * 16 + g * 4;
        const int bb = m0 >> 11, t0 = m0 & 2047;
        #pragma unroll
        for (int ni = 0; ni < 2; ++ni) {
            const int n = col0 + wc * 32 + ni * 16 + lr;
            const int h = n >> 6, dh = n & 63;
            #pragma unroll
            for (int r = 0; r < 4; ++r) {
                float v = acc[mi][ni][r];
                if (z == 2) v = 1.0f / (1.0f + __expf(-(v + gbias[n])));
                C[(((size_t)(bb * NH + h)) * NT + (t0 + r)) * DH + dh] = v;
            }
        }
    }
}

// ---------- bf16 MFMA GEMM (Wo path, fp32 row-major out) ----------
__global__ __launch_bounds__(256) void gemm_bf16_kernel(
    const ushort* __restrict__ Ab, const ushort* __restrict__ Bb,
    float* __restrict__ Cp)
{
    __shared__ ushort Al[128][40];
    __shared__ ushort Bl[64][40];
    const int tid = threadIdx.x;
    const int l = tid & 63, w = tid >> 6;
    const int wr = w >> 1, wc = w & 1;
    const int lr = l & 15, g = l >> 4;
    const int row0 = blockIdx.y * 128, col0 = blockIdx.x * 64;
    f32x4 acc[4][2];
    #pragma unroll
    for (int mi = 0; mi < 4; ++mi)
        #pragma unroll
        for (int ni = 0; ni < 2; ++ni) acc[mi][ni] = (f32x4){0.f, 0.f, 0.f, 0.f};
    const int sa_row = tid >> 1, sa_half = (tid & 1) * 16;
    const int sb_row = tid >> 2, sb_q = (tid & 3) * 8;
    const ushort* Ap = Ab + (size_t)(row0 + sa_row) * DM + sa_half;
    const ushort* Bp = Bb + (size_t)(col0 + sb_row) * DM + sb_q;
    for (int k0 = 0; k0 < DM; k0 += 32) {
        const uint4 a0 = *(const uint4*)(Ap + k0);
        const uint4 a1 = *(const uint4*)(Ap + k0 + 8);
        const uint4 b0 = *(const uint4*)(Bp + k0);
        __syncthreads();
        *(uint4*)&Al[sa_row][sa_half]     = a0;
        *(uint4*)&Al[sa_row][sa_half + 8] = a1;
        *(uint4*)&Bl[sb_row][sb_q]        = b0;
        __syncthreads();
        bf8 a[4], b[2];
        #pragma unroll
        for (int mi = 0; mi < 4; ++mi) a[mi] = *(const bf8*)&Al[wr * 64 + mi * 16 + lr][g * 8];
        #pragma unroll
        for (int ni = 0; ni < 2; ++ni) b[ni] = *(const bf8*)&Bl[wc * 32 + ni * 16 + lr][g * 8];
        #pragma unroll
        for (int mi = 0; mi < 4; ++mi)
            #pragma unroll
            for (int ni = 0; ni < 2; ++ni)
                acc[mi][ni] = __builtin_amdgcn_mfma_f32_16x16x32_bf16(a[mi], b[ni], acc[mi][ni], 0, 0, 0);
    }
    #pragma unroll
    for (int mi = 0; mi < 4; ++mi) {
        const int m0 = row0 + wr * 64 + mi * 16 + g * 4;
        #pragma unroll
        for (int ni = 0; ni < 2; ++ni) {
            const int n = col0 + wc * 32 + ni * 16 + lr;
            #pragma unroll
            for (int r = 0; r < 4; ++r)
                Cp[(size_t)(m0 + r) * DM + n] = acc[mi][ni][r];
        }
    }
}

// -------- nrw + fused scan-pre --------
__global__ __launch_bounds__(256) void nrw_kernel(
    const float* __restrict__ qraw, const float* __restrict__ kraw,
    const float* __restrict__ Amat, float* __restrict__ gateq,
    ushort* __restrict__ kgb,
    float* __restrict__ kcoefA, float* __restrict__ R0A,
    float* __restrict__ R1A, float* __restrict__ r15A)
{
    __shared__ float S[64][64];
    __shared__ float zq[4][64];
    __shared__ float zk[4][64];
    const int bh = blockIdx.x;
    const int h = bh & (NH - 1);
    const int tid = threadIdx.x;
    const int g = tid >> 6, lane = tid & 63;
    for (int idx = tid; idx < 4096; idx += 256) {
        const int d = idx >> 6, e = idx & 63;
        S[d][e] = Amat[(size_t)h * 4096 + d * 64 + e] - Amat[(size_t)h * 4096 + e * 64 + d];
    }
    __syncthreads();
    const int j = lane & 31;
    const float invf = powf(10000.0f, -(float)(2 * j) * (1.0f / 64.0f));
    const int t0 = blockIdx.y * 64 + g * 16;
    float kc0 = 0.f, kc1 = 0.f, run = 0.f, Ra0 = 0.f, Ra1 = 0.f;
    for (int r = 0; r < 16; ++r) {
        const int t = t0 + r;
        const size_t base = ((size_t)bh * NT + t) * DH;
        const float qv = qraw[base + lane];
        const float kv = kraw[base + lane];
        float sq = qv, sk = kv, qq = qv * qv, kk2 = kv * kv;
        #pragma unroll
        for (int off = 32; off; off >>= 1) {
            sq += __shfl_xor(sq, off);
            sk += __shfl_xor(sk, off);
            qq += __shfl_xor(qq, off);
            kk2 += __shfl_xor(kk2, off);
        }
        const float mq = sq * (1.0f / 64.0f), mk = sk * (1.0f / 64.0f);
        const float vq = (qq - 64.0f * mq * mq) * (1.0f / 63.0f);
        const float vk = (kk2 - 64.0f * mk * mk) * (1.0f / 63.0f);
        const float ms = 0.5f * (mq + mk);
        const float ss = 0.5f * (sqrtf(fmaxf(vq, 0.0f)) + sqrtf(fmaxf(vk, 0.0f)));
        const float rinv = 1.0f / (ss + 1e-6f);
        const float qn = (qv - ms) * rinv;
        const float kn = (kv - ms) * rinv;
        const float q1 = __shfl(qn, 2 * j), q2 = __shfl(qn, 2 * j + 1);
        const float k1 = __shfl(kn, 2 * j), k2 = __shfl(kn, 2 * j + 1);
        float sn, cs;
        sincosf((float)t * invf, &sn, &cs);
        const float rq = (lane < 32) ? (q1 * cs - q2 * sn) : (q1 * sn + q2 * cs);
        const float rk = (lane < 32) ? (k1 * cs - k2 * sn) : (k1 * sn + k2 * cs);
        zq[g][lane] = rq;
        zk[g][lane] = rk;
        float aq = 0.0f, ak = 0.0f;
        #pragma unroll 8
        for (int d = 0; d < 64; ++d) {
            const float sde = S[d][lane];
            aq = fmaf(zq[g][d], sde, aq);
            ak = fmaf(zk[g][d], sde, ak);
        }
        const float qgv = rq + aq;
        const float kgv = rk + ak;
        const float gv = gateq[base + lane];
        const float qgpv = gv * qgv;
        gateq[base + lane] = qgpv;
        kgb[base + lane] = f2bf(kgv);
        kc0 = fmaf(kgv, 0.25f, kc0);
        kc1 = fmaf(kgv, wbf(r, 1), kc1);
        run += qgpv;
        Ra0 = fmaf(run, 0.25f, Ra0);
        Ra1 = fmaf(run, wbf(r, 1), Ra1);
    }
    const int unit = bh * 128 + blockIdx.y * 4 + g;
    kcoefA[(size_t)unit * 128 + lane] = kc0;
    kcoefA[(size_t)unit * 128 + 64 + lane] = kc1;
    R0A[(size_t)unit * 64 + lane] = Ra0;
    R1A[(size_t)unit * 64 + lane] = Ra1;
    r15A[(size_t)unit * 64 + lane] = run;
}

// -------- merged: blocks 0..31 serial scan (shfl-free inner); blocks 32+ V-projection GEMM --------
__global__ __launch_bounds__(256) void scan_vgemm_kernel(
    const float* __restrict__ kcoefA, const float* __restrict__ R0A,
    const float* __restrict__ R1A, const float* __restrict__ r15A,
    const float* __restrict__ jscale, const float* __restrict__ jbias,
    float* __restrict__ r0O, float* __restrict__ r1O,
    float* __restrict__ lpO, float* __restrict__ jgO,
    const ushort* __restrict__ xb, const ushort* __restrict__ Wb,
    ushort* __restrict__ Vt)
{
    __shared__ char smem[100864];
    if (blockIdx.x >= 32) {
        const int gi = blockIdx.x - 32;
        const int col0 = (gi & 15) * 64;
        const int row0 = (gi >> 4) * 128;
        ushort (*Al)[40] = (ushort(*)[40])smem;
        ushort (*Bl)[40] = (ushort(*)[40])(smem + 10240);
        const int tid = threadIdx.x;
        const int l = tid & 63, w = tid >> 6;
        const int wr = w >> 1, wc = w & 1;
        const int lr = l & 15, g = l >> 4;
        f32x4 acc[4][2];
        #pragma unroll
        for (int mi = 0; mi < 4; ++mi)
            #pragma unroll
            for (int ni = 0; ni < 2; ++ni) acc[mi][ni] = (f32x4){0.f, 0.f, 0.f, 0.f};
        const int sa_row = tid >> 1, sa_half = (tid & 1) * 16;
        const int sb_row = tid >> 2, sb_q = (tid & 3) * 8;
        const ushort* Ap = xb + (size_t)(row0 + sa_row) * DM + sa_half;
        const ushort* Bp = Wb + (size_t)(col0 + sb_row) * DM + sb_q;
        for (int k0 = 0; k0 < DM; k0 += 32) {
            const uint4 a0 = *(const uint4*)(Ap + k0);
            const uint4 a1 = *(const uint4*)(Ap + k0 + 8);
            const uint4 b0 = *(const uint4*)(Bp + k0);
            __syncthreads();
            *(uint4*)&Al[sa_row][sa_half]     = a0;
            *(uint4*)&Al[sa_row][sa_half + 8] = a1;
            *(uint4*)&Bl[sb_row][sb_q]        = b0;
            __syncthreads();
            bf8 a[4], b[2];
            #pragma unroll
            for (int mi = 0; mi < 4; ++mi) a[mi] = *(const bf8*)&Al[wr * 64 + mi * 16 + lr][g * 8];
            #pragma unroll
            for (int ni = 0; ni < 2; ++ni) b[ni] = *(const bf8*)&Bl[wc * 32 + ni * 16 + lr][g * 8];
            #pragma unroll
            for (int mi = 0; mi < 4; ++mi)
                #pragma unroll
                for (int ni = 0; ni < 2; ++ni)
                    acc[mi][ni] = __builtin_amdgcn_mfma_f32_16x16x32_bf16(a[mi], b[ni], acc[mi][ni], 0, 0, 0);
        }
        #pragma unroll
        for (int mi = 0; mi < 4; ++mi) {
            const int m0 = row0 + wr * 64 + mi * 16 + g * 4;
            const int bb = m0 >> 11, t0 = m0 & 2047;
            #pragma unroll
            for (int ni = 0; ni < 2; ++ni) {
                const int n = col0 + wc * 32 + ni * 16 + lr;
                const int h = n >> 6, dh = n & 63;
                ushort4 pk;
                pk.x = f2bf(acc[mi][ni][0]); pk.y = f2bf(acc[mi][ni][1]);
                pk.z = f2bf(acc[mi][ni][2]); pk.w = f2bf(acc[mi][ni][3]);
                *(ushort4*)(Vt + (((size_t)(bb * NH + h)) * DH + dh) * NT + t0) = pk;
            }
        }
        return;
    }
    if (threadIdx.x >= 64) return;
    float* HA  = (float*)smem;
    float* KcL = (float*)(smem + 65536);
    float* EL  = (float*)(smem + 73728);
    float* ET  = (float*)(smem + 82176);
    float* VP  = (float*)(smem + 92416);
    float* mxold = (float*)(smem + 100608);
    float* psold = (float*)(smem + 100672);
    float* pbuf  = (float*)(smem + 100736);
    float* qbuf    = (float*)(smem + 73728);   // aliases EL (dead during serial inner)
    float* candBuf = (float*)(smem + 74752);
    const int bh = blockIdx.x;
    const int l = threadIdx.x;
    #pragma unroll
    for (int c = 0; c < 64; ++c)
        *(f32x4*)&HA[c * 256 + l * 4] = (f32x4){0.f, 0.f, 0.f, 0.f};
    const float js = jscale[0], jb = jbias[0];
    const float* kcp  = kcoefA + (size_t)bh * 128 * 128;
    const float* R0p  = R0A  + (size_t)bh * 128 * 64;
    const float* R1p  = R1A  + (size_t)bh * 128 * 64;
    const float* r15p = r15A + (size_t)bh * 128 * 64;
    float* r0o = r0O + (size_t)bh * 128 * 64;
    float* r1o = r1O + (size_t)bh * 128 * 64;
    float* lpo = lpO + (size_t)bh * 128 * 64;
    float* jgo = jgO + (size_t)bh * 128;
    float last = 0.0f;
    const float wb15_1 = wbf(15, 1);
    const int iiq = l >> 2, sq = l & 3;
    const int ch = l >> 2;

    for (int j = 0; j < 8; ++j) {
        const int P = 16 * j;
        #pragma unroll
        for (int t = 0; t < 8; ++t)
            *(f32x4*)&KcL[t * 256 + l * 4] = *(const f32x4*)&kcp[j * 2048 + t * 256 + l * 4];
        float R0b[16], R1b[16], r15b[16];
        #pragma unroll
        for (int t = 0; t < 16; ++t) {
            R0b[t]  = R0p[(P + t) * 64 + l];
            R1b[t]  = R1p[(P + t) * 64 + l];
            r15b[t] = r15p[(P + t) * 64 + l];
        }
        {
            float sA[16], sB[16];
            #pragma unroll
            for (int ii = 0; ii < 16; ++ii) { sA[ii] = 0.f; sB[ii] = 0.f; }
            const int swA = l & 31;
            for (int c = 0; c < 32; ++c) {
                const int cs = ((c ^ swA) << 2);
                const f32x4 hA = *(const f32x4*)&HA[l * 128 + cs];
                const f32x4 hB = *(const f32x4*)&HA[(64 + l) * 128 + cs];
                #pragma unroll
                for (int ii = 0; ii < 16; ++ii) {
                    const f32x4 kc = *(const f32x4*)&KcL[ii * 128 + (c << 2)];
                    sA[ii] = fmaf(hA[0], kc[0], sA[ii]); sA[ii] = fmaf(hA[1], kc[1], sA[ii]);
                    sA[ii] = fmaf(hA[2], kc[2], sA[ii]); sA[ii] = fmaf(hA[3], kc[3], sA[ii]);
                    sB[ii] = fmaf(hB[0], kc[0], sB[ii]); sB[ii] = fmaf(hB[1], kc[1], sB[ii]);
                    sB[ii] = fmaf(hB[2], kc[2], sB[ii]); sB[ii] = fmaf(hB[3], kc[3], sB[ii]);
                }
            }
            #pragma unroll
            for (int ii = 0; ii < 16; ++ii) {
                if (l < P)      EL[ii * 132 + l]      = sA[ii] * 0.125f;
                if (64 + l < P) EL[ii * 132 + 64 + l] = sB[ii] * 0.125f;
            }
        }
        {
            float m = -1e30f;
            for (int n = sq; n < P; n += 4) m = fmaxf(m, EL[iiq * 132 + n]);
            m = fmaxf(m, __shfl_xor(m, 1));
            m = fmaxf(m, __shfl_xor(m, 2));
            if (sq == 0) mxold[iiq] = m;
        }
        {
            const float mo = (P > 0) ? mxold[iiq] : -1e30f;
            float ps = 0.f;
            for (int n = sq; n < P; n += 4) {
                const float e = __expf(EL[iiq * 132 + n] - mo);
                ET[n * 20 + iiq] = e;
                ps += e;
            }
            ps += __shfl_xor(ps, 1);
            ps += __shfl_xor(ps, 2);
            if (sq == 0) psold[iiq] = ps;
        }
        {
            float vp0[16], vp1[16];
            #pragma unroll
            for (int ii = 0; ii < 16; ++ii) { vp0[ii] = 0.f; vp1[ii] = 0.f; }
            for (int n = 0; n < P; ++n) {
                const int sw = n & 31;
                const float h0 = HA[n * 128 + ((ch ^ sw) << 2) + (l & 3)];
                const float h1 = HA[n * 128 + (((16 + ch) ^ sw) << 2) + (l & 3)];
                const f32x4 e0 = *(const f32x4*)&ET[n * 20];
                const f32x4 e1 = *(const f32x4*)&ET[n * 20 + 4];
                const f32x4 e2 = *(const f32x4*)&ET[n * 20 + 8];
                const f32x4 e3 = *(const f32x4*)&ET[n * 20 + 12];
                #pragma unroll
                for (int u = 0; u < 4; ++u) {
                    vp0[u]      = fmaf(e0[u], h0, vp0[u]);      vp1[u]      = fmaf(e0[u], h1, vp1[u]);
                    vp0[4 + u]  = fmaf(e1[u], h0, vp0[4 + u]);  vp1[4 + u]  = fmaf(e1[u], h1, vp1[4 + u]);
                    vp0[8 + u]  = fmaf(e2[u], h0, vp0[8 + u]);  vp1[8 + u]  = fmaf(e2[u], h1, vp1[8 + u]);
                    vp0[12 + u] = fmaf(e3[u], h0, vp0[12 + u]); vp1[12 + u] = fmaf(e3[u], h1, vp1[12 + u]);
                }
            }
            #pragma unroll
            for (int ii = 0; ii < 16; ++ii) {
                VP[ii * 128 + l]      = vp0[ii];
                VP[ii * 128 + 64 + l] = vp1[ii];
            }
        }
        const int n_ = l >> 2, q = l & 3;
        const int qb = l & ~3;
        #pragma unroll
        for (int iL = 0; iL < 16; ++iL) {
            const int i = P + iL;
            const int nrow = P + n_;
            const int nsw = nrow & 31;
            float scp = 0.f;
            #pragma unroll
            for (int c = 0; c < 8; ++c) {
                const f32x4 h  = *(const f32x4*)&HA[nrow * 128 + ((((q << 3) + c) ^ nsw) << 2)];
                const f32x4 kc = *(const f32x4*)&KcL[iL * 128 + (q << 5) + (c << 2)];
                scp = fmaf(h[0], kc[0], scp); scp = fmaf(h[1], kc[1], scp);
                scp = fmaf(h[2], kc[2], scp); scp = fmaf(h[3], kc[3], scp);
            }
            qbuf[l] = scp;
            const float scn = (qbuf[qb] + qbuf[qb + 1]) + (qbuf[qb + 2] + qbuf[qb + 3]);
            const float cand = (n_ < iL) ? scn * 0.125f : -1e30f;
            if (q == 0) candBuf[n_] = cand;
            float m8[8];
            #pragma unroll
            for (int u = 0; u < 8; ++u) m8[u] = fmaxf(candBuf[2 * u], candBuf[2 * u + 1]);
            float m4a = fmaxf(m8[0], m8[1]), m4b = fmaxf(m8[2], m8[3]);
            float m4c = fmaxf(m8[4], m8[5]), m4d = fmaxf(m8[6], m8[7]);
            const float mxn = fmaxf(fmaxf(m4a, m4b), fmaxf(m4c, m4d));
            const float mo = mxold[iL];
            const float mx = fmaxf(mxn, mo);
            const float p = (n_ < iL) ? __expf(cand - mx) : 0.f;
            if (q == 0) pbuf[n_] = p;
            float s8[8];
            #pragma unroll
            for (int u = 0; u < 8; ++u) s8[u] = pbuf[2 * u] + pbuf[2 * u + 1];
            float s4a = s8[0] + s8[1], s4b = s8[2] + s8[3];
            float s4c = s8[4] + s8[5], s4d = s8[6] + s8[7];
            const float psn = (s4a + s4b) + (s4c + s4d);
            float r0 = 0.f, r1 = 0.f;
            if (i > 0) {
                const float so = __expf(mo - mx);
                float racc0 = VP[iL * 128 + l] * so;
                float racc1 = VP[iL * 128 + 64 + l] * so;
                #pragma unroll
                for (int n2 = 0; n2 < iL; ++n2) {
                    const float pn = pbuf[n2];
                    const int nr = P + n2;
                    const int sw2 = nr & 31;
                    racc0 = fmaf(pn, HA[nr * 128 + ((ch ^ sw2) << 2) + (l & 3)], racc0);
                    racc1 = fmaf(pn, HA[nr * 128 + (((16 + ch) ^ sw2) << 2) + (l & 3)], racc1);
                }
                const float ps = fmaf(psold[iL], so, psn);
                const float rden = 1.0f / ps;
                r0 = racc0 * rden;
                r1 = racc1 * rden;
            }
            const float jg = 1.0f / (1.0f + __expf(-fmaf(mx, js, jb)));
            const float lastp = last;
            const float h0n = R0b[iL] + fmaf(jg, r0, 4.0f * (1.0f - jg) * lastp);
            const float h1n = fmaf(jg, r1, R1b[iL]);
            const float qrec15 = fmaf(r0, 0.25f, r1 * wb15_1);
            last = r15b[iL] + fmaf(jg, qrec15, (1.0f - jg) * lastp);
            r0o[i * 64 + l] = r0;
            r1o[i * 64 + l] = r1;
            lpo[i * 64 + l] = lastp;
            if (l == 0) jgo[i] = jg;
            const int swi = i & 31;
            HA[i * 128 + ((ch ^ swi) << 2) + (l & 3)] = h0n;
            HA[i * 128 + (((16 + ch) ^ swi) << 2) + (l & 3)] = h1n;
        }
    }
}

// -------- scan post-pass: Qout = cumsum(qgp) + inj --------
__global__ __launch_bounds__(256) void scan_post_kernel(
    const float* __restrict__ qgp, const float* __restrict__ r0O,
    const float* __restrict__ r1O, const float* __restrict__ lpO,
    const float* __restrict__ jgO, float* __restrict__ Qout)
{
    const int unit = blockIdx.x * 4 + (threadIdx.x >> 6);
    const int d = threadIdx.x & 63;
    const int bh = unit >> 7, i = unit & 127;
    const size_t ub = (size_t)unit * 64 + d;
    const float r0 = r0O[ub], r1 = r1O[ub], lp = lpO[ub];
    const float jg = jgO[unit];
    const size_t cbase = ((size_t)bh * NT + i * 16) * DH + d;
    float run = 0.0f;
    #pragma unroll
    for (int ll = 0; ll < 16; ++ll) {
        run += qgp[cbase + ll * 64];
        const float qrec = fmaf(r0, 0.25f, r1 * wbf(ll, 1));
        const float inj = (i > 0) ? fmaf(jg, qrec, (1.0f - jg) * lp) : 0.0f;
        Qout[cbase + ll * 64] = run + inj;
    }
}

// -------- MFMA flash attention v2: KVBLK=64, split [40]-stride LDS, per-lane lrow --------
__global__ __launch_bounds__(256) void attn_mfma_kernel(
    const float* __restrict__ Qf, const ushort* __restrict__ Kb,
    const ushort* __restrict__ Vtb, const float* __restrict__ sink,
    const float* __restrict__ vnull, ushort* __restrict__ Ob)
{
    __shared__ ushort Kl0[64][40], Kl1[64][40];
    __shared__ ushort Vl0[64][40], Vl1[64][40];
    __shared__ ushort Pl[4][2][16][40];
    const int bh = blockIdx.y;
    const int h = bh & (NH - 1);
    const int b = bh >> 4;
    const int qt = gridDim.x - 1 - blockIdx.x;
    const int q0 = qt * 64;
    const int tid = threadIdx.x;
    const int w = tid >> 6, l = tid & 63;
    const int lr = l & 15, g = l >> 4;
    bf8 qf[2];
    {
        const float* qp = Qf + (((size_t)bh * NT) + q0 + 16 * w + lr) * DH + g * 8;
        #pragma unroll
        for (int ks = 0; ks < 2; ++ks) {
            const float4 f0 = *(const float4*)(qp + 32 * ks);
            const float4 f1 = *(const float4*)(qp + 32 * ks + 4);
            bf8 q;
            q[0] = (short)f2bf(f0.x); q[1] = (short)f2bf(f0.y);
            q[2] = (short)f2bf(f0.z); q[3] = (short)f2bf(f0.w);
            q[4] = (short)f2bf(f1.x); q[5] = (short)f2bf(f1.y);
            q[6] = (short)f2bf(f1.z); q[7] = (short)f2bf(f1.w);
            qf[ks] = q;
        }
    }
    f32x4 oacc[4];
    #pragma unroll
    for (int nf2 = 0; nf2 < 4; ++nf2) oacc[nf2] = (f32x4){0.f, 0.f, 0.f, 0.f};
    float mrow[4], lrowp[4];
    #pragma unroll
    for (int r = 0; r < 4; ++r) { mrow[r] = -1e30f; lrowp[r] = 0.0f; }
    const int ntiles = qt + 1;
    const ushort* Kg = Kb + (size_t)bh * NT * DH;
    const ushort* Vg = Vtb + (size_t)bh * DH * NT;
    const int srow = tid >> 2;
    const int sc16 = (tid & 3) * 16;
    for (int it = 0; it < ntiles; ++it) {
        const int kv0 = it * 64;
        __syncthreads();
        {
            const ushort* kp = Kg + (size_t)(kv0 + srow) * DH + sc16;
            const ushort* vp = Vg + (size_t)srow * NT + kv0 + sc16;
            ushort* kd = (sc16 < 32) ? &Kl0[srow][sc16] : &Kl1[srow][sc16 - 32];
            ushort* vd = (sc16 < 32) ? &Vl0[srow][sc16] : &Vl1[srow][sc16 - 32];
            *(uint4*)kd       = *(const uint4*)kp;
            *(uint4*)(kd + 8) = *(const uint4*)(kp + 8);
            *(uint4*)vd       = *(const uint4*)vp;
            *(uint4*)(vd + 8) = *(const uint4*)(vp + 8);
        }
        __syncthreads();
        f32x4 s[4];
        #pragma unroll
        for (int nf = 0; nf < 4; ++nf) {
            s[nf] = (f32x4){0.f, 0.f, 0.f, 0.f};
            const bf8 kf0 = *(const bf8*)&Kl0[nf * 16 + lr][g * 8];
            const bf8 kf1 = *(const bf8*)&Kl1[nf * 16 + lr][g * 8];
            s[nf] = __builtin_amdgcn_mfma_f32_16x16x32_bf16(qf[0], kf0, s[nf], 0, 0, 0);
            s[nf] = __builtin_amdgcn_mfma_f32_16x16x32_bf16(qf[1], kf1, s[nf], 0, 0, 0);
        }
        #pragma unroll
        for (int r = 0; r < 4; ++r) {
            const int row = q0 + 16 * w + g * 4 + r;
            float sv[4];
            float tmax = -1e30f;
            #pragma unroll
            for (int nf = 0; nf < 4; ++nf) {
                const int col = kv0 + nf * 16 + lr;
                sv[nf] = (col <= row) ? s[nf][r] * 0.125f : -1e30f;
                tmax = fmaxf(tmax, sv[nf]);
            }
            tmax = fmaxf(tmax, __shfl_xor(tmax, 1));
            tmax = fmaxf(tmax, __shfl_xor(tmax, 2));
            tmax = fmaxf(tmax, __shfl_xor(tmax, 4));
            tmax = fmaxf(tmax, __shfl_xor(tmax, 8));
            const float mnew = fmaxf(mrow[r], tmax);
            const float csc = __expf(mrow[r] - mnew);
            float plocal = 0.f;
            #pragma unroll
            for (int nf = 0; nf < 4; ++nf) {
                const float p = __expf(sv[nf] - mnew);
                plocal += p;
                Pl[w][nf >> 1][g * 4 + r][(nf & 1) * 16 + lr] = f2bf(p);
            }
            lrowp[r] = lrowp[r] * csc + plocal;
            mrow[r] = mnew;
            #pragma unroll
            for (int nf2 = 0; nf2 < 4; ++nf2) oacc[nf2][r] *= csc;
        }
        const bf8 pa0 = *(const bf8*)&Pl[w][0][lr][g * 8];
        const bf8 pa1 = *(const bf8*)&Pl[w][1][lr][g * 8];
        #pragma unroll
        for (int nf2 = 0; nf2 < 4; ++nf2) {
            const bf8 vb0 = *(const bf8*)&Vl0[nf2 * 16 + lr][g * 8];
            const bf8 vb1 = *(const bf8*)&Vl1[nf2 * 16 + lr][g * 8];
            oacc[nf2] = __builtin_amdgcn_mfma_f32_16x16x32_bf16(pa0, vb0, oacc[nf2], 0, 0, 0);
            oacc[nf2] = __builtin_amdgcn_mfma_f32_16x16x32_bf16(pa1, vb1, oacc[nf2], 0, 0, 0);
        }
    }
    float lrow[4];
    #pragma unroll
    for (int r = 0; r < 4; ++r) {
        float ps = lrowp[r];
        ps += __shfl_xor(ps, 1);
        ps += __shfl_xor(ps, 2);
        ps += __shfl_xor(ps, 4);
        ps += __shfl_xor(ps, 8);
        lrow[r] = ps;
    }
    const float s0 = sink[h];
    float c0v[4], pnv[4], rden[4];
    #pragma unroll
    for (int r = 0; r < 4; ++r) {
        const float mf = fmaxf(mrow[r], s0);
        c0v[r] = __expf(mrow[r] - mf);
        pnv[r] = __expf(s0 - mf);
        rden[r] = 1.0f / fmaf(lrow[r], c0v[r], pnv[r]);
    }
    #pragma unroll
    for (int nf2 = 0; nf2 < 4; ++nf2) {
        const float vn = vnull[h * DH + nf2 * 16 + lr];
        #pragma unroll
        for (int r = 0; r < 4; ++r) {
            const float out = fmaf(pnv[r], vn, oacc[nf2][r] * c0v[r]) * rden[r];
            const int trow = q0 + 16 * w + g * 4 + r;
            Ob[(((size_t)b * NT) + trow) * DM + h * DH + nf2 * 16 + lr] = f2bf(out);
        }
    }
}

extern "C" void kernel_launch(void* const* d_in, const int* in_sizes, int n_in,
                              void* d_out, int out_size, void* d_ws, size_t ws_size,
                              hipStream_t stream) {
    const float* x     = (const float*)d_in[0];
    const float* Wq    = (const float*)d_in[1];
    const float* Wk    = (const float*)d_in[2];
    const float* Wv    = (const float*)d_in[3];
    const float* Wo    = (const float*)d_in[4];
    const float* gw    = (const float*)d_in[5];
    const float* gbias = (const float*)d_in[6];
    const float* Amat  = (const float*)d_in[7];
    const float* js    = (const float*)d_in[8];
    const float* jb    = (const float*)d_in[9];
    const float* sink  = (const float*)d_in[10];
    const float* vnull = (const float*)d_in[11];
    char* ws = (char*)d_ws;
    const size_t MB = 1024 * 1024;
    float*  q_raw  = (float*)(ws + 0);
    float*  k_raw  = (float*)(ws + 16 * MB);
    float*  gate   = (float*)(ws + 32 * MB);
    ushort* kgb    = (ushort*)(ws + 64 * MB);
    ushort* xb     = (ushort*)(ws + 72 * MB);
    ushort* Wb     = (ushort*)(ws + 80 * MB);
    float*  kcoefA = (float*)(ws + 84 * MB);
    float*  R0A    = (float*)(ws + 86 * MB);
    float*  R1A    = (float*)(ws + 87 * MB);
    float*  r15A   = (float*)(ws + 88 * MB);
    float*  r0O    = (float*)(ws + 89 * MB);
    float*  r1O    = (float*)(ws + 90 * MB);
    float*  lpO    = (float*)(ws + 91 * MB);
    float*  jgO    = (float*)(ws + 92 * MB);
    ushort* Vt     = (ushort*)k_raw;
    ushort* attob  = (ushort*)(ws + 24 * MB);

    cast3_kernel<<<6144, 256, 0, stream>>>(x, Wv, Wo, xb, Wb);
    gemm3m_kernel<<<dim3(DM / 64, (NB * NT) / 128, 3), 256, 0, stream>>>(
        x, Wq, Wk, gw, gbias, q_raw, k_raw, gate);
    nrw_kernel<<<dim3(NB * NH, NT / 64), 256, 0, stream>>>(
        q_raw, k_raw, Amat, gate, kgb, kcoefA, R0A, R1A, r15A);
    scan_vgemm_kernel<<<32 + 512, 256, 0, stream>>>(
        kcoefA, R0A, R1A, r15A, js, jb, r0O, r1O, lpO, jgO, xb, Wb, Vt);
    scan_post_kernel<<<1024, 256, 0, stream>>>(gate, r0O, r1O, lpO, jgO, q_raw);
    attn_mfma_kernel<<<dim3(NT / 64, NB * NH), 256, 0, stream>>>(q_raw, kgb, Vt, sink, vnull, attob);
    gemm_bf16_kernel<<<dim3(DM / 64, (NB * NT) / 128), 256, 0, stream>>>(
        attob, Wb + DM * DM, (float*)d_out);
}